// Round 16
// baseline (113.226 us; speedup 1.0000x reference)
//
#include <hip/hip_runtime.h>

#define N_NODES 16384
#define N_EDGES 262144
#define D 256
#define B_GRAPHS 32
#define NODES_PER_GRAPH 512   // N_NODES / B_GRAPHS
#define MAXDEG 64             // Poisson(16): P(deg>64) ~ 1e-17

// ---------------------------------------------------------------------------
// zero cnt
// ---------------------------------------------------------------------------
__global__ __launch_bounds__(256) void zero_cnt_kernel(int* __restrict__ cnt) {
    cnt[blockIdx.x * 256 + threadIdx.x] = 0;
}

// ---------------------------------------------------------------------------
// bucket fill: col[dst*64 + slot] = src
// ---------------------------------------------------------------------------
__global__ __launch_bounds__(256) void fill_bucket_kernel(const int* __restrict__ edge,
                                                          int* __restrict__ cnt,
                                                          int* __restrict__ col) {
    int e = blockIdx.x * 256 + threadIdx.x;
    int dst = edge[N_EDGES + e];
    int src = edge[e];
    int slot = atomicAdd(&cnt[dst], 1);
    if (slot < MAXDEG) col[dst * MAXDEG + slot] = src;
}

// ---------------------------------------------------------------------------
// aggx: A[i] = mean_{j in in(i)} x[j]   (full graph, f32, one wave per node)
// ---------------------------------------------------------------------------
__global__ __launch_bounds__(256) void aggx_kernel(const float* __restrict__ x,
                                                   const int* __restrict__ cnt,
                                                   const int* __restrict__ col,
                                                   float* __restrict__ A) {
    int node = blockIdx.x * 4 + (threadIdx.x >> 6);
    int lane = threadIdx.x & 63;
    int c = cnt[node];
    if (c > MAXDEG) c = MAXDEG;
    int my = (lane < c) ? col[node * MAXDEG + lane] : 0;
    float a0 = 0.f, a1 = 0.f, a2 = 0.f, a3 = 0.f;
    int j = 0;
    for (; j + 8 <= c; j += 8) {
        float4 v[8];
        #pragma unroll
        for (int q = 0; q < 8; ++q) {
            int s = __shfl(my, j + q);
            v[q] = *(const float4*)&x[(size_t)s * D + lane * 4];
        }
        #pragma unroll
        for (int q = 0; q < 8; ++q) {
            a0 += v[q].x; a1 += v[q].y; a2 += v[q].z; a3 += v[q].w;
        }
    }
    for (; j < c; ++j) {
        int s = __shfl(my, j);
        float4 v = *(const float4*)&x[(size_t)s * D + lane * 4];
        a0 += v.x; a1 += v.y; a2 += v.z; a3 += v.w;
    }
    float id = 1.0f / (float)(c < 1 ? 1 : c);
    float4 r = make_float4(a0 * id, a1 * id, a2 * id, a3 * id);
    *(float4*)&A[(size_t)node * D + lane * 4] = r;
}

// ---------------------------------------------------------------------------
// aggB: for each (root, slot<cnt[root]) pair, n = col[root*64+slot]:
//   B[root*64+slot] = mean_{m in in(n)} A[m]
// One wave per pair: 2048 waves, 512 blocks — high parallelism for the
// latency-bound 2-hop gather that the 32-block tail serialized (R14: 45us).
// ---------------------------------------------------------------------------
__global__ __launch_bounds__(256) void aggB_kernel(const float* __restrict__ A,
                                                   const int* __restrict__ cnt,
                                                   const int* __restrict__ col,
                                                   float* __restrict__ B) {
    int wg = blockIdx.x * 4 + (threadIdx.x >> 6);  // 0..2047
    int r = wg >> 6;                               // graph id
    int slot = wg & 63;
    int lane = threadIdx.x & 63;
    int root = r * NODES_PER_GRAPH;
    int c0 = cnt[root]; if (c0 > MAXDEG) c0 = MAXDEG;
    if (slot >= c0) return;
    int n = col[root * MAXDEG + slot];
    int c = cnt[n]; if (c > MAXDEG) c = MAXDEG;
    int my = (lane < c) ? col[n * MAXDEG + lane] : 0;
    float a0 = 0.f, a1 = 0.f, a2 = 0.f, a3 = 0.f;
    int j = 0;
    for (; j + 8 <= c; j += 8) {
        float4 v[8];
        #pragma unroll
        for (int q = 0; q < 8; ++q) {
            int s = __shfl(my, j + q);
            v[q] = *(const float4*)&A[(size_t)s * D + lane * 4];
        }
        #pragma unroll
        for (int q = 0; q < 8; ++q) {
            a0 += v[q].x; a1 += v[q].y; a2 += v[q].z; a3 += v[q].w;
        }
    }
    for (; j < c; ++j) {
        int s = __shfl(my, j);
        float4 v = *(const float4*)&A[(size_t)s * D + lane * 4];
        a0 += v.x; a1 += v.y; a2 += v.z; a3 += v.w;
    }
    float id = 1.0f / (float)(c < 1 ? 1 : c);
    float4 out = make_float4(a0 * id, a1 * id, a2 * id, a3 * id);
    *(float4*)&B[(size_t)wg * D + lane * 4] = out;
}

// ---------------------------------------------------------------------------
// Telescoped tail (one block per graph, 1024 threads, f32):
//   g0=x[r], g1=A[r], g2=mean_s A[col[r,s]], g3=mean_s B[r,s]
//   v0=g1@Wl1+g0@Wr1+b1 ; v1=g2@Wl1+g1@Wr1+b1 ; v2=g3@Wl1+g2@Wr1+b1
//   hB=v1@Wl2+v0@Wr2+b2 ; hA=v2@Wl2+v1@Wr2+b2
//   h =hA@Wl3+hB@Wr3+b3 ; out = MLP head(h)
// GEMVs: thread (kq=t>>6, c4=t&63), float4 W loads, 16 fully unrolled.
// ---------------------------------------------------------------------------
__global__ __launch_bounds__(1024) void tail_kernel(
    const int* __restrict__ cnt, const int* __restrict__ col,
    const float* __restrict__ x, const float* __restrict__ A,
    const float* __restrict__ B,
    const float* __restrict__ Wl, const float* __restrict__ bl,
    const float* __restrict__ Wr,
    const float* __restrict__ Wh, const float* __restrict__ bh,
    const float* __restrict__ Wo, const float* __restrict__ bo,
    float* __restrict__ out)
{
    __shared__ float g0[D], g1[D], g2[D], g3[D];
    __shared__ float v0[D], v1[D], v2[D], hA[D], hB[D];
    __shared__ float part[3][16][D];
    __shared__ int snr;

    const int b = blockIdx.x, t = threadIdx.x;
    const int w = t >> 6, lane = t & 63;
    const int root = b * NODES_PER_GRAPH;

    if (t == 0) { int cc = cnt[root]; snr = (cc > MAXDEG) ? MAXDEG : cc; }
    if (t < D) {
        g0[t] = x[(size_t)root * D + t];
        g1[t] = A[(size_t)root * D + t];
    }
    __syncthreads();
    const int c0 = snr;

    // ---- light gathers: g2 from A rows, g3 from B rows ----
    {
        float p1[4] = {0.f, 0.f, 0.f, 0.f}, p2[4] = {0.f, 0.f, 0.f, 0.f};
        for (int i = w; i < c0; i += 16) {
            int n = col[root * MAXDEG + i];
            float4 va = *(const float4*)&A[(size_t)n * D + lane * 4];
            float4 vb = *(const float4*)&B[(size_t)(b * MAXDEG + i) * D + lane * 4];
            p1[0] += va.x; p1[1] += va.y; p1[2] += va.z; p1[3] += va.w;
            p2[0] += vb.x; p2[1] += vb.y; p2[2] += vb.z; p2[3] += vb.w;
        }
        #pragma unroll
        for (int q = 0; q < 4; ++q) {
            part[0][w][lane * 4 + q] = p1[q];
            part[1][w][lane * 4 + q] = p2[q];
        }
        __syncthreads();
        if (t < D) {
            float s1 = 0.f, s2 = 0.f;
            #pragma unroll
            for (int ww = 0; ww < 16; ++ww) { s1 += part[0][ww][t]; s2 += part[1][ww][t]; }
            float id0 = 1.0f / (float)(c0 < 1 ? 1 : c0);
            g2[t] = s1 * id0;
            g3[t] = s2 * id0;
        }
        __syncthreads();
    }

    const int kq = t >> 6, c4 = t & 63;
    // ---- layer 1: v0, v1, v2 in one pass over Wl1/Wr1 (float4 loads) ----
    {
        const float4* WL = (const float4*)Wl;
        const float4* WR = (const float4*)Wr;
        float4 a0 = {0,0,0,0}, a1 = {0,0,0,0}, a2 = {0,0,0,0};
        #pragma unroll
        for (int k0 = 0; k0 < 16; ++k0) {
            int k = kq * 16 + k0;
            float4 wl = WL[(size_t)k * 64 + c4];
            float4 wr = WR[(size_t)k * 64 + c4];
            float h1 = g1[k], h0 = g0[k], h2 = g2[k], h3 = g3[k];
            a0.x += h1 * wl.x + h0 * wr.x; a0.y += h1 * wl.y + h0 * wr.y;
            a0.z += h1 * wl.z + h0 * wr.z; a0.w += h1 * wl.w + h0 * wr.w;
            a1.x += h2 * wl.x + h1 * wr.x; a1.y += h2 * wl.y + h1 * wr.y;
            a1.z += h2 * wl.z + h1 * wr.z; a1.w += h2 * wl.w + h1 * wr.w;
            a2.x += h3 * wl.x + h2 * wr.x; a2.y += h3 * wl.y + h2 * wr.y;
            a2.z += h3 * wl.z + h2 * wr.z; a2.w += h3 * wl.w + h2 * wr.w;
        }
        *(float4*)&part[0][kq][c4 * 4] = a0;
        *(float4*)&part[1][kq][c4 * 4] = a1;
        *(float4*)&part[2][kq][c4 * 4] = a2;
        __syncthreads();
        if (t < D) {
            float s0 = 0.f, s1 = 0.f, s2 = 0.f;
            #pragma unroll
            for (int i = 0; i < 16; ++i) {
                s0 += part[0][i][t]; s1 += part[1][i][t]; s2 += part[2][i][t];
            }
            float bb = bl[t];
            v0[t] = s0 + bb; v1[t] = s1 + bb; v2[t] = s2 + bb;
        }
        __syncthreads();
    }
    // ---- layer 2: hA = v2@Wl2 + v1@Wr2 + b2 ; hB = v1@Wl2 + v0@Wr2 + b2 ----
    {
        const float4* WL = (const float4*)(Wl + (size_t)1 * D * D);
        const float4* WR = (const float4*)(Wr + (size_t)1 * D * D);
        float4 aA = {0,0,0,0}, aB = {0,0,0,0};
        #pragma unroll
        for (int k0 = 0; k0 < 16; ++k0) {
            int k = kq * 16 + k0;
            float4 wl = WL[(size_t)k * 64 + c4];
            float4 wr = WR[(size_t)k * 64 + c4];
            float h2 = v2[k], h1 = v1[k], h0 = v0[k];
            aA.x += h2 * wl.x + h1 * wr.x; aA.y += h2 * wl.y + h1 * wr.y;
            aA.z += h2 * wl.z + h1 * wr.z; aA.w += h2 * wl.w + h1 * wr.w;
            aB.x += h1 * wl.x + h0 * wr.x; aB.y += h1 * wl.y + h0 * wr.y;
            aB.z += h1 * wl.z + h0 * wr.z; aB.w += h1 * wl.w + h0 * wr.w;
        }
        *(float4*)&part[0][kq][c4 * 4] = aA;
        *(float4*)&part[1][kq][c4 * 4] = aB;
        __syncthreads();
        if (t < D) {
            float sA = 0.f, sB = 0.f;
            #pragma unroll
            for (int i = 0; i < 16; ++i) { sA += part[0][i][t]; sB += part[1][i][t]; }
            float bb = bl[D + t];
            hA[t] = sA + bb; hB[t] = sB + bb;
        }
        __syncthreads();
    }
    // ---- layer 3: v0 <- hA@Wl3 + hB@Wr3 + b3 (head input) ----
    {
        const float4* WL = (const float4*)(Wl + (size_t)2 * D * D);
        const float4* WR = (const float4*)(Wr + (size_t)2 * D * D);
        float4 a = {0,0,0,0};
        #pragma unroll
        for (int k0 = 0; k0 < 16; ++k0) {
            int k = kq * 16 + k0;
            float4 wl = WL[(size_t)k * 64 + c4];
            float4 wr = WR[(size_t)k * 64 + c4];
            float ha = hA[k], hb = hB[k];
            a.x += ha * wl.x + hb * wr.x; a.y += ha * wl.y + hb * wr.y;
            a.z += ha * wl.z + hb * wr.z; a.w += ha * wl.w + hb * wr.w;
        }
        *(float4*)&part[0][kq][c4 * 4] = a;
        __syncthreads();
        if (t < D) {
            float s = 0.f;
            #pragma unroll
            for (int i = 0; i < 16; ++i) s += part[0][i][t];
            v0[t] = s + bl[2 * D + t];
        }
        __syncthreads();
    }
    // ---- MLP head ----
    for (int l = 0; l < 3; ++l) {
        const float4* W = (const float4*)((l < 2) ? Wh + (size_t)l * D * D : Wo);
        float4 a = {0,0,0,0};
        #pragma unroll
        for (int k0 = 0; k0 < 16; ++k0) {
            int k = kq * 16 + k0;
            float4 wv = W[(size_t)k * 64 + c4];
            float hk = v0[k];
            a.x += hk * wv.x; a.y += hk * wv.y; a.z += hk * wv.z; a.w += hk * wv.w;
        }
        *(float4*)&part[0][kq][c4 * 4] = a;
        __syncthreads();
        if (t < D) {
            float s = 0.f;
            #pragma unroll
            for (int i = 0; i < 16; ++i) s += part[0][i][t];
            float v = s + ((l < 2) ? bh[(size_t)l * D + t] : bo[t]);
            if (l < 2) v0[t] = fmaxf(v, 0.f);
            else       out[(size_t)b * D + t] = v;
        }
        __syncthreads();
    }
}

// ---------------------------------------------------------------------------
extern "C" void kernel_launch(void* const* d_in, const int* in_sizes, int n_in,
                              void* d_out, int out_size, void* d_ws, size_t ws_size,
                              hipStream_t stream) {
    const float* x    = (const float*)d_in[0];
    const int*   edge = (const int*)d_in[1];
    const float* Wl   = (const float*)d_in[2];
    const float* bl   = (const float*)d_in[3];
    const float* Wr   = (const float*)d_in[4];
    const float* Wh   = (const float*)d_in[5];
    const float* bh   = (const float*)d_in[6];
    const float* Wo   = (const float*)d_in[7];
    const float* bo   = (const float*)d_in[8];
    float* out = (float*)d_out;

    char* w = (char*)d_ws;
    auto alloc = [&](size_t bytes) {
        char* p = w;
        w += (bytes + 255) & ~(size_t)255;
        return p;
    };
    int*   cnt = (int*)  alloc((size_t)N_NODES * 4);
    int*   col = (int*)  alloc((size_t)N_NODES * MAXDEG * 4);
    float* A   = (float*)alloc((size_t)N_NODES * D * 4);
    float* B   = (float*)alloc((size_t)B_GRAPHS * MAXDEG * D * 4);

    zero_cnt_kernel<<<N_NODES / 256, 256, 0, stream>>>(cnt);
    fill_bucket_kernel<<<N_EDGES / 256, 256, 0, stream>>>(edge, cnt, col);
    aggx_kernel<<<N_NODES / 4, 256, 0, stream>>>(x, cnt, col, A);
    aggB_kernel<<<512, 256, 0, stream>>>(A, cnt, col, B);
    tail_kernel<<<B_GRAPHS, 1024, 0, stream>>>(cnt, col, x, A, B,
                                               Wl, bl, Wr, Wh, bh, Wo, bo, out);
}

// Round 17
// 104.979 us; speedup vs baseline: 1.0786x; 1.0786x over previous
//
#include <hip/hip_runtime.h>

#define N_NODES 16384
#define N_EDGES 262144
#define D 256
#define B_GRAPHS 32
#define NODES_PER_GRAPH 512   // N_NODES / B_GRAPHS
#define MAXDEG 64             // Poisson(16): P(deg>64) ~ 1e-17

// ---------------------------------------------------------------------------
// zero cnt
// ---------------------------------------------------------------------------
__global__ __launch_bounds__(256) void zero_cnt_kernel(int* __restrict__ cnt) {
    cnt[blockIdx.x * 256 + threadIdx.x] = 0;
}

// ---------------------------------------------------------------------------
// bucket fill: col[dst*64 + slot] = src
// ---------------------------------------------------------------------------
__global__ __launch_bounds__(256) void fill_bucket_kernel(const int* __restrict__ edge,
                                                          int* __restrict__ cnt,
                                                          int* __restrict__ col) {
    int e = blockIdx.x * 256 + threadIdx.x;
    int dst = edge[N_EDGES + e];
    int src = edge[e];
    int slot = atomicAdd(&cnt[dst], 1);
    if (slot < MAXDEG) col[dst * MAXDEG + slot] = src;
}

// ---------------------------------------------------------------------------
// aggx: A[i] = mean_{j in in(i)} x[j]   (full graph, f32, one wave per node)
// ---------------------------------------------------------------------------
__global__ __launch_bounds__(256) void aggx_kernel(const float* __restrict__ x,
                                                   const int* __restrict__ cnt,
                                                   const int* __restrict__ col,
                                                   float* __restrict__ A) {
    int node = blockIdx.x * 4 + (threadIdx.x >> 6);
    int lane = threadIdx.x & 63;
    int c = cnt[node];
    if (c > MAXDEG) c = MAXDEG;
    int my = (lane < c) ? col[node * MAXDEG + lane] : 0;
    float a0 = 0.f, a1 = 0.f, a2 = 0.f, a3 = 0.f;
    int j = 0;
    for (; j + 8 <= c; j += 8) {
        float4 v[8];
        #pragma unroll
        for (int q = 0; q < 8; ++q) {
            int s = __shfl(my, j + q);
            v[q] = *(const float4*)&x[(size_t)s * D + lane * 4];
        }
        #pragma unroll
        for (int q = 0; q < 8; ++q) {
            a0 += v[q].x; a1 += v[q].y; a2 += v[q].z; a3 += v[q].w;
        }
    }
    for (; j < c; ++j) {
        int s = __shfl(my, j);
        float4 v = *(const float4*)&x[(size_t)s * D + lane * 4];
        a0 += v.x; a1 += v.y; a2 += v.z; a3 += v.w;
    }
    float id = 1.0f / (float)(c < 1 ? 1 : c);
    float4 r = make_float4(a0 * id, a1 * id, a2 * id, a3 * id);
    *(float4*)&A[(size_t)node * D + lane * 4] = r;
}

// ---------------------------------------------------------------------------
// Telescoped tail (one block per graph, 1024 threads, f32):
//   g0=x[r], g1=A[r], g2=mean_{n in(r)} A[n], g3=mean_n mean_{m in(n)} A[m]
//   v0=g1@Wl1+g0@Wr1+b1 ; v1=g2@Wl1+g1@Wr1+b1 ; v2=g3@Wl1+g2@Wr1+b1
//   hB=v1@Wl2+v0@Wr2+b2 ; hA=v2@Wl2+v1@Wr2+b2
//   h =hA@Wl3+hB@Wr3+b3 ; out = MLP head(h)
// GEMVs: thread (kq=t>>6, c4=t&63); float4 W loads in 8-wide batches
// (16 loads in flight on dual-W phases). launch_bounds(1024,4) -> 128 VGPR cap
// so the batches stay in registers instead of being latency-chunked.
// ---------------------------------------------------------------------------
__global__ __launch_bounds__(1024, 4) void tail_kernel(
    const int* __restrict__ cnt, const int* __restrict__ col,
    const float* __restrict__ x, const float* __restrict__ A,
    const float* __restrict__ Wl, const float* __restrict__ bl,
    const float* __restrict__ Wr,
    const float* __restrict__ Wh, const float* __restrict__ bh,
    const float* __restrict__ Wo, const float* __restrict__ bo,
    float* __restrict__ out)
{
    __shared__ float g0[D], g1[D], g2[D], g3[D];
    __shared__ float v0[D], v1[D], v2[D], hA[D], hB[D];
    __shared__ float part[3][16][D];
    __shared__ int nbr[MAXDEG];
    __shared__ int snr;

    const int b = blockIdx.x, t = threadIdx.x;
    const int w = t >> 6, lane = t & 63;
    const int root = b * NODES_PER_GRAPH;

    if (t == 0) { int cc = cnt[root]; snr = (cc > MAXDEG) ? MAXDEG : cc; }
    __syncthreads();
    const int c0 = snr;
    if (t < c0) nbr[t] = col[root * MAXDEG + t];
    if (t < D) {
        g0[t] = x[(size_t)root * D + t];
        g1[t] = A[(size_t)root * D + t];
    }
    __syncthreads();

    // ---- 1/2-hop gathers of A (R14-proven): wave w owns neighbors w,w+16,.. ----
    {
        float p1[4] = {0.f, 0.f, 0.f, 0.f}, p2[4] = {0.f, 0.f, 0.f, 0.f};
        for (int i = w; i < c0; i += 16) {
            int n = nbr[i];
            {
                float4 v = *(const float4*)&A[(size_t)n * D + lane * 4];
                p1[0] += v.x; p1[1] += v.y; p1[2] += v.z; p1[3] += v.w;
            }
            int c = cnt[n]; if (c > MAXDEG) c = MAXDEG;
            int my = (lane < c) ? col[n * MAXDEG + lane] : 0;
            float a[4] = {0.f, 0.f, 0.f, 0.f};
            int j = 0;
            for (; j + 4 <= c; j += 4) {
                float4 v[4];
                #pragma unroll
                for (int q = 0; q < 4; ++q) {
                    int s = __shfl(my, j + q);
                    v[q] = *(const float4*)&A[(size_t)s * D + lane * 4];
                }
                #pragma unroll
                for (int q = 0; q < 4; ++q) {
                    a[0] += v[q].x; a[1] += v[q].y; a[2] += v[q].z; a[3] += v[q].w;
                }
            }
            for (; j < c; ++j) {
                int s = __shfl(my, j);
                float4 v = *(const float4*)&A[(size_t)s * D + lane * 4];
                a[0] += v.x; a[1] += v.y; a[2] += v.z; a[3] += v.w;
            }
            float id = 1.0f / (float)(c < 1 ? 1 : c);
            #pragma unroll
            for (int q = 0; q < 4; ++q) p2[q] += a[q] * id;
        }
        #pragma unroll
        for (int q = 0; q < 4; ++q) {
            part[0][w][lane * 4 + q] = p1[q];
            part[1][w][lane * 4 + q] = p2[q];
        }
        __syncthreads();
        if (t < D) {
            float s1 = 0.f, s2 = 0.f;
            #pragma unroll
            for (int ww = 0; ww < 16; ++ww) { s1 += part[0][ww][t]; s2 += part[1][ww][t]; }
            float id0 = 1.0f / (float)(c0 < 1 ? 1 : c0);
            g2[t] = s1 * id0;
            g3[t] = s2 * id0;
        }
        __syncthreads();
    }

    const int kq = t >> 6, c4 = t & 63;

    // ---- layer 1: v0,v1,v2 in one pass over Wl1/Wr1 (batched float4) ----
    {
        const float4* WL = (const float4*)Wl;
        const float4* WR = (const float4*)Wr;
        float4 a0 = {0,0,0,0}, a1 = {0,0,0,0}, a2 = {0,0,0,0};
        for (int kb = 0; kb < 16; kb += 8) {
            float4 wl[8], wr[8];
            #pragma unroll
            for (int q = 0; q < 8; ++q) {
                int k = kq * 16 + kb + q;
                wl[q] = WL[(size_t)k * 64 + c4];
                wr[q] = WR[(size_t)k * 64 + c4];
            }
            #pragma unroll
            for (int q = 0; q < 8; ++q) {
                int k = kq * 16 + kb + q;
                float h0 = g0[k], h1 = g1[k], h2 = g2[k], h3 = g3[k];
                a0.x += h1 * wl[q].x + h0 * wr[q].x;
                a0.y += h1 * wl[q].y + h0 * wr[q].y;
                a0.z += h1 * wl[q].z + h0 * wr[q].z;
                a0.w += h1 * wl[q].w + h0 * wr[q].w;
                a1.x += h2 * wl[q].x + h1 * wr[q].x;
                a1.y += h2 * wl[q].y + h1 * wr[q].y;
                a1.z += h2 * wl[q].z + h1 * wr[q].z;
                a1.w += h2 * wl[q].w + h1 * wr[q].w;
                a2.x += h3 * wl[q].x + h2 * wr[q].x;
                a2.y += h3 * wl[q].y + h2 * wr[q].y;
                a2.z += h3 * wl[q].z + h2 * wr[q].z;
                a2.w += h3 * wl[q].w + h2 * wr[q].w;
            }
        }
        *(float4*)&part[0][kq][c4 * 4] = a0;
        *(float4*)&part[1][kq][c4 * 4] = a1;
        *(float4*)&part[2][kq][c4 * 4] = a2;
        __syncthreads();
        if (t < D) {
            float s0 = 0.f, s1 = 0.f, s2 = 0.f;
            #pragma unroll
            for (int i = 0; i < 16; ++i) {
                s0 += part[0][i][t]; s1 += part[1][i][t]; s2 += part[2][i][t];
            }
            float bb = bl[t];
            v0[t] = s0 + bb; v1[t] = s1 + bb; v2[t] = s2 + bb;
        }
        __syncthreads();
    }
    // ---- layer 2: hA = v2@Wl2+v1@Wr2+b2 ; hB = v1@Wl2+v0@Wr2+b2 ----
    {
        const float4* WL = (const float4*)(Wl + (size_t)1 * D * D);
        const float4* WR = (const float4*)(Wr + (size_t)1 * D * D);
        float4 aA = {0,0,0,0}, aB = {0,0,0,0};
        for (int kb = 0; kb < 16; kb += 8) {
            float4 wl[8], wr[8];
            #pragma unroll
            for (int q = 0; q < 8; ++q) {
                int k = kq * 16 + kb + q;
                wl[q] = WL[(size_t)k * 64 + c4];
                wr[q] = WR[(size_t)k * 64 + c4];
            }
            #pragma unroll
            for (int q = 0; q < 8; ++q) {
                int k = kq * 16 + kb + q;
                float h2 = v2[k], h1 = v1[k], h0 = v0[k];
                aA.x += h2 * wl[q].x + h1 * wr[q].x;
                aA.y += h2 * wl[q].y + h1 * wr[q].y;
                aA.z += h2 * wl[q].z + h1 * wr[q].z;
                aA.w += h2 * wl[q].w + h1 * wr[q].w;
                aB.x += h1 * wl[q].x + h0 * wr[q].x;
                aB.y += h1 * wl[q].y + h0 * wr[q].y;
                aB.z += h1 * wl[q].z + h0 * wr[q].z;
                aB.w += h1 * wl[q].w + h0 * wr[q].w;
            }
        }
        *(float4*)&part[0][kq][c4 * 4] = aA;
        *(float4*)&part[1][kq][c4 * 4] = aB;
        __syncthreads();
        if (t < D) {
            float sA = 0.f, sB = 0.f;
            #pragma unroll
            for (int i = 0; i < 16; ++i) { sA += part[0][i][t]; sB += part[1][i][t]; }
            float bb = bl[D + t];
            hA[t] = sA + bb; hB[t] = sB + bb;
        }
        __syncthreads();
    }
    // ---- layer 3: v0 <- hA@Wl3 + hB@Wr3 + b3 (head input) ----
    {
        const float4* WL = (const float4*)(Wl + (size_t)2 * D * D);
        const float4* WR = (const float4*)(Wr + (size_t)2 * D * D);
        float4 a = {0,0,0,0};
        for (int kb = 0; kb < 16; kb += 8) {
            float4 wl[8], wr[8];
            #pragma unroll
            for (int q = 0; q < 8; ++q) {
                int k = kq * 16 + kb + q;
                wl[q] = WL[(size_t)k * 64 + c4];
                wr[q] = WR[(size_t)k * 64 + c4];
            }
            #pragma unroll
            for (int q = 0; q < 8; ++q) {
                int k = kq * 16 + kb + q;
                float ha = hA[k], hb = hB[k];
                a.x += ha * wl[q].x + hb * wr[q].x;
                a.y += ha * wl[q].y + hb * wr[q].y;
                a.z += ha * wl[q].z + hb * wr[q].z;
                a.w += ha * wl[q].w + hb * wr[q].w;
            }
        }
        *(float4*)&part[0][kq][c4 * 4] = a;
        __syncthreads();
        if (t < D) {
            float s = 0.f;
            #pragma unroll
            for (int i = 0; i < 16; ++i) s += part[0][i][t];
            v0[t] = s + bl[2 * D + t];
        }
        __syncthreads();
    }
    // ---- MLP head: 16 float4 fully in flight (single W per layer) ----
    for (int l = 0; l < 3; ++l) {
        const float4* W = (const float4*)((l < 2) ? Wh + (size_t)l * D * D : Wo);
        float4 a = {0,0,0,0};
        {
            float4 wv[16];
            #pragma unroll
            for (int q = 0; q < 16; ++q)
                wv[q] = W[(size_t)(kq * 16 + q) * 64 + c4];
            #pragma unroll
            for (int q = 0; q < 16; ++q) {
                float hk = v0[kq * 16 + q];
                a.x += hk * wv[q].x; a.y += hk * wv[q].y;
                a.z += hk * wv[q].z; a.w += hk * wv[q].w;
            }
        }
        *(float4*)&part[0][kq][c4 * 4] = a;
        __syncthreads();
        if (t < D) {
            float s = 0.f;
            #pragma unroll
            for (int i = 0; i < 16; ++i) s += part[0][i][t];
            float v = s + ((l < 2) ? bh[(size_t)l * D + t] : bo[t]);
            if (l < 2) v0[t] = fmaxf(v, 0.f);
            else       out[(size_t)b * D + t] = v;
        }
        __syncthreads();
    }
}

// ---------------------------------------------------------------------------
extern "C" void kernel_launch(void* const* d_in, const int* in_sizes, int n_in,
                              void* d_out, int out_size, void* d_ws, size_t ws_size,
                              hipStream_t stream) {
    const float* x    = (const float*)d_in[0];
    const int*   edge = (const int*)d_in[1];
    const float* Wl   = (const float*)d_in[2];
    const float* bl   = (const float*)d_in[3];
    const float* Wr   = (const float*)d_in[4];
    const float* Wh   = (const float*)d_in[5];
    const float* bh   = (const float*)d_in[6];
    const float* Wo   = (const float*)d_in[7];
    const float* bo   = (const float*)d_in[8];
    float* out = (float*)d_out;

    char* w = (char*)d_ws;
    auto alloc = [&](size_t bytes) {
        char* p = w;
        w += (bytes + 255) & ~(size_t)255;
        return p;
    };
    int*   cnt = (int*)  alloc((size_t)N_NODES * 4);
    int*   col = (int*)  alloc((size_t)N_NODES * MAXDEG * 4);
    float* A   = (float*)alloc((size_t)N_NODES * D * 4);

    zero_cnt_kernel<<<N_NODES / 256, 256, 0, stream>>>(cnt);
    fill_bucket_kernel<<<N_EDGES / 256, 256, 0, stream>>>(edge, cnt, col);
    aggx_kernel<<<N_NODES / 4, 256, 0, stream>>>(x, cnt, col, A);
    tail_kernel<<<B_GRAPHS, 1024, 0, stream>>>(cnt, col, x, A,
                                               Wl, bl, Wr, Wh, bh, Wo, bo, out);
}